// Round 20
// baseline (145.436 us; speedup 1.0000x reference)
//
#include <hip/hip_runtime.h>
#include <stdint.h>

#define S_LEN 4096
#define D_EMB 1024
#define NH 16
#define DHEAD 64
#define N3 3072

typedef __attribute__((ext_vector_type(8))) short short8;
typedef __attribute__((ext_vector_type(4))) short short4v;
typedef __attribute__((ext_vector_type(4))) float f32x4;

// workspace layout (ushort elements)
#define OFF_XB    0u         // x bf16 [4096][1024]
#define OFF_WINT  4194304u   // W_in^T bf16
#define OFF_WOUTT 7340032u   // W_out^T bf16 (live until gemm2)
#define OFF_Q     8388608u   // q [H][S][64], k [H][S][64], v^T [H][64][S]
#define OFF_ATTN  20971520u  // attn out [4096][1024] bf16

// 0.125 (1/sqrt(64)) * log2(e)
#define QSCALE 0.1803368801111204f
#define DEFER_THR 11.0f

__device__ __forceinline__ unsigned short f2bf(float f) {
  unsigned u = __float_as_uint(f);
  unsigned r = u + 0x7FFFu + ((u >> 16) & 1u);
  return (unsigned short)(r >> 16);
}
__device__ __forceinline__ unsigned cvtpk_bf16(float lo, float hi) {
  unsigned r;
  asm("v_cvt_pk_bf16_f32 %0, %1, %2" : "=v"(r) : "v"(lo), "v"(hi));
  return r;
}
__device__ __forceinline__ void gload16(const void* g, void* l) {
  __builtin_amdgcn_global_load_lds((const __attribute__((address_space(1))) void*)g,
                                   (__attribute__((address_space(3))) void*)l, 16, 0, 0);
}

// ---------------- fused prep (r19) ----------------
__global__ __launch_bounds__(256) void prep_kernel(const float* __restrict__ x,
                                                   const float* __restrict__ W_in,
                                                   const float* __restrict__ W_out,
                                                   ushort* __restrict__ xb,
                                                   ushort* __restrict__ wint,
                                                   ushort* __restrict__ woutt) {
  __shared__ float tile[32][65];
  int b = blockIdx.x;
  int tid = threadIdx.x;
  if (b < 4096) {
    int i = (b * 256 + tid) * 4;
    float4 v = *(const float4*)(x + i);
    ushort4 o;
    o.x = f2bf(v.x); o.y = f2bf(v.y); o.z = f2bf(v.z); o.w = f2bf(v.w);
    *(ushort4*)(xb + i) = o;
    return;
  }
  const float* src;
  ushort* dst;
  int C, bx, by;
  if (b < 5632) {
    int t = b - 4096;
    src = W_in; dst = wint; C = N3;
    bx = t % 48; by = t / 48;
  } else {
    int t = b - 5632;
    src = W_out; dst = woutt; C = D_EMB;
    bx = t & 15; by = t >> 4;
  }
  const int R = D_EMB;
  int r0 = by * 32, c0 = bx * 64;
  int lr = tid >> 3, lc8 = (tid & 7) * 8;
  float4 v0 = *(const float4*)&src[(size_t)(r0 + lr) * C + c0 + lc8];
  float4 v1 = *(const float4*)&src[(size_t)(r0 + lr) * C + c0 + lc8 + 4];
  tile[lr][lc8 + 0] = v0.x; tile[lr][lc8 + 1] = v0.y;
  tile[lr][lc8 + 2] = v0.z; tile[lr][lc8 + 3] = v0.w;
  tile[lr][lc8 + 4] = v1.x; tile[lr][lc8 + 5] = v1.y;
  tile[lr][lc8 + 6] = v1.z; tile[lr][lc8 + 7] = v1.w;
  __syncthreads();
  int oc = tid >> 2, q = tid & 3;
  short8 o;
#pragma unroll
  for (int i = 0; i < 8; ++i) o[i] = (short)f2bf(tile[q * 8 + i][oc]);
  *(short8*)&dst[(size_t)(c0 + oc) * R + r0 + q * 8] = o;
}

// ---------------- GEMM1: 256x192 tile, 256 blocks, 8-phase counted-vmcnt (r18) ----------------
__global__ __launch_bounds__(512, 2) void gemm1_8phase(const ushort* __restrict__ A,
                                                       const ushort* __restrict__ Bt,
                                                       const float* __restrict__ bias,
                                                       ushort* __restrict__ o16) {
  __shared__ ushort L[57344];
  const int K = 1024;
  int tid = threadIdx.x, w = tid >> 6, lane = tid & 63;
  int wr = w >> 2, wc = w & 3;
  int l15 = lane & 15, g = lane >> 4;
  int lr = lane >> 3, lc = lane & 7;
  int swcol = (lc ^ lr) * 8;
  int rxor = (l15 & 7) << 3;
  int id = blockIdx.y * 16 + blockIdx.x;
  int id2 = (id & 7) * 32 + (id >> 3);
  int bm = (id2 >> 4) * 256, bn = (id2 & 15) * 192;

  f32x4 acc[8][3];
#pragma unroll
  for (int m = 0; m < 8; ++m)
#pragma unroll
    for (int n = 0; n < 3; ++n) acc[m][n] = (f32x4){0.f, 0.f, 0.f, 0.f};

  auto stageA = [&](int t, int h) {
#pragma unroll
    for (int r2 = 0; r2 < 2; ++r2)
      gload16(A + (size_t)(bm + h * 128 + r2 * 64 + w * 8 + lr) * K + t * 64 + swcol,
              &L[(t & 1) * 16384 + h * 8192 + r2 * 4096 + w * 512]);
  };
  auto stageB0 = [&](int t) {
#pragma unroll
    for (int r2 = 0; r2 < 2; ++r2)
      gload16(Bt + (size_t)(bn + r2 * 64 + w * 8 + lr) * K + t * 64 + swcol,
              &L[32768 + (t & 1) * 12288 + r2 * 4096 + w * 512]);
  };
  auto stageB1 = [&](int t) {
    gload16(Bt + (size_t)(bn + 128 + w * 8 + lr) * K + t * 64 + swcol,
            &L[32768 + (t & 1) * 12288 + 8192 + w * 512]);
  };

  short8 bf[3][2], af[2][2];
  auto readB = [&](int tb) {
    int base = 32768 + tb * 12288;
#pragma unroll
    for (int n = 0; n < 3; ++n)
#pragma unroll
      for (int ks = 0; ks < 2; ++ks)
        bf[n][ks] = *(const short8*)&L[base + (wc * 48 + n * 16 + l15) * 64 + ((ks * 32 + g * 8) ^ rxor)];
  };
  auto readA2 = [&](int tb, int m0) {
    int base = tb * 16384 + wr * 8192;
#pragma unroll
    for (int mi = 0; mi < 2; ++mi)
#pragma unroll
      for (int ks = 0; ks < 2; ++ks)
        af[mi][ks] = *(const short8*)&L[base + ((m0 + mi) * 16 + l15) * 64 + ((ks * 32 + g * 8) ^ rxor)];
  };
  auto mfma6 = [&](int m0) {
#pragma unroll
    for (int mi = 0; mi < 2; ++mi)
#pragma unroll
      for (int n = 0; n < 3; ++n)
#pragma unroll
        for (int ks = 0; ks < 2; ++ks)
          acc[m0 + mi][n] =
              __builtin_amdgcn_mfma_f32_16x16x32_bf16(af[mi][ks], bf[n][ks], acc[m0 + mi][n], 0, 0, 0);
  };

#define BAR() __builtin_amdgcn_s_barrier()
#define LGK0() asm volatile("s_waitcnt lgkmcnt(0)" ::: "memory")
#define VM3() asm volatile("s_waitcnt vmcnt(3)" ::: "memory")
#define VM0() asm volatile("s_waitcnt vmcnt(0)" ::: "memory")

  stageA(0, 0); stageA(0, 1); stageB0(0); stageB1(0);
  stageB0(1); stageB1(1);
  VM3();
  BAR();

  for (int i = 0; i < 8; ++i) {
    int T = 2 * i;
    bool more = (T + 2 < 16);
    readB(0); readA2(0, 0); stageA(T + 1, 0);
    BAR(); LGK0();
    __builtin_amdgcn_s_setprio(1); mfma6(0); __builtin_amdgcn_s_setprio(0);
    BAR();
    readA2(0, 2); stageA(T + 1, 1);
    BAR(); LGK0();
    __builtin_amdgcn_s_setprio(1); mfma6(2); __builtin_amdgcn_s_setprio(0);
    BAR();
    readA2(0, 4); if (more) stageB0(T + 2);
    BAR(); LGK0();
    __builtin_amdgcn_s_setprio(1); mfma6(4); __builtin_amdgcn_s_setprio(0);
    BAR();
    readA2(0, 6); if (more) stageB1(T + 2);
    BAR(); LGK0();
    __builtin_amdgcn_s_setprio(1); mfma6(6); __builtin_amdgcn_s_setprio(0);
    if (more) VM3(); else VM0();
    BAR();
    readB(1); readA2(1, 0); if (more) stageA(T + 2, 0);
    BAR(); LGK0();
    __builtin_amdgcn_s_setprio(1); mfma6(0); __builtin_amdgcn_s_setprio(0);
    BAR();
    readA2(1, 2); if (more) stageA(T + 2, 1);
    BAR(); LGK0();
    __builtin_amdgcn_s_setprio(1); mfma6(2); __builtin_amdgcn_s_setprio(0);
    BAR();
    readA2(1, 4); if (more) stageB0(T + 3);
    BAR(); LGK0();
    __builtin_amdgcn_s_setprio(1); mfma6(4); __builtin_amdgcn_s_setprio(0);
    BAR();
    readA2(1, 6); if (more) stageB1(T + 3);
    BAR(); LGK0();
    __builtin_amdgcn_s_setprio(1); mfma6(6); __builtin_amdgcn_s_setprio(0);
    if (more) VM3(); else VM0();
    BAR();
  }
#undef BAR
#undef LGK0
#undef VM3
#undef VM0

#pragma unroll
  for (int m = 0; m < 8; ++m) {
    int rbase = bm + wr * 128 + m * 16 + g * 4;
#pragma unroll
    for (int n = 0; n < 3; ++n) {
      int c = bn + wc * 48 + n * 16 + l15;
      float bv = bias[c];
      int which = c >> 10, cc = c & 1023, hh = cc >> 6, dcol = cc & 63;
      if (which == 2) {
        ushort4 o;
        o.x = f2bf(acc[m][n][0] + bv);
        o.y = f2bf(acc[m][n][1] + bv);
        o.z = f2bf(acc[m][n][2] + bv);
        o.w = f2bf(acc[m][n][3] + bv);
        *(ushort4*)&o16[8388608u + (size_t)hh * (DHEAD * (size_t)S_LEN) +
                        (size_t)dcol * S_LEN + rbase] = o;
      } else {
        float qs = (which == 0) ? QSCALE : 1.0f;
        ushort* dst = o16 + (size_t)which * 4194304u +
                      (size_t)hh * (S_LEN * DHEAD) + dcol;
#pragma unroll
        for (int j = 0; j < 4; ++j)
          dst[(size_t)(rbase + j) * DHEAD] = f2bf((acc[m][n][j] + bv) * qs);
      }
    }
  }
}

// ---------------- GEMM2: 128x64 tile, 3-buffer counted-vmcnt pipeline (r17) ----------------
#define BK 64

__global__ __launch_bounds__(256) void gemm2_kernel(const ushort* __restrict__ A,
                                                    const ushort* __restrict__ Bt,
                                                    const float* __restrict__ bias,
                                                    float* __restrict__ o32,
                                                    int N, int K) {
  __shared__ ushort L[36864];
  int tid = threadIdx.x, w = tid >> 6, lane = tid & 63;
  int wr = w >> 1, wc = w & 1;
  int l15 = lane & 15, g = lane >> 4;
  int lr = lane >> 3, lc = lane & 7;
  int swcol = (lc ^ lr) * 8;
  int rxor = (l15 & 7) << 3;
  int gx = gridDim.x;
  int id = blockIdx.y * gx + blockIdx.x;
  int q8 = (gx * gridDim.y) >> 3;
  int id2 = (id & 7) * q8 + (id >> 3);
  int bm = (id2 / gx) * 128, bn = (id2 % gx) * 64;
  f32x4 acc[4][2];
#pragma unroll
  for (int m = 0; m < 4; ++m)
#pragma unroll
    for (int n = 0; n < 2; ++n) acc[m][n] = (f32x4){0.f, 0.f, 0.f, 0.f};

  auto stage = [&](int t) {
    int buf = t % 3;
#pragma unroll
    for (int i = 0; i < 4; ++i) {
      int ch = w * 4 + i;
      gload16(A + (size_t)(bm + ch * 8 + lr) * K + t * 64 + swcol,
              &L[buf * 8192 + ch * 512]);
    }
#pragma unroll
    for (int i = 0; i < 2; ++i) {
      int ch = w * 2 + i;
      gload16(Bt + (size_t)(bn + ch * 8 + lr) * K + t * 64 + swcol,
              &L[24576 + buf * 4096 + ch * 512]);
    }
  };

  const int NT = 16;
  stage(0); stage(1);
  asm volatile("s_waitcnt vmcnt(6)" ::: "memory");
  __builtin_amdgcn_s_barrier();

  for (int t = 0; t < NT; ++t) {
    int buf = t % 3;
    if (t + 2 < NT) stage(t + 2);
    const ushort* Ab = &L[buf * 8192];
    const ushort* Bb = &L[24576 + buf * 4096];
    short8 a[4][2], b[2][2];
#pragma unroll
    for (int m = 0; m < 4; ++m)
#pragma unroll
      for (int ks = 0; ks < 2; ++ks)
        a[m][ks] = *(const short8*)&Ab[(wr * 64 + m * 16 + l15) * 64 + ((ks * 32 + g * 8) ^ rxor)];
#pragma unroll
    for (int n = 0; n < 2; ++n)
#pragma unroll
      for (int ks = 0; ks < 2; ++ks)
        b[n][ks] = *(const short8*)&Bb[(wc * 32 + n * 16 + l15) * 64 + ((ks * 32 + g * 8) ^ rxor)];
    asm volatile("s_waitcnt lgkmcnt(0)" ::: "memory");
    __builtin_amdgcn_s_setprio(1);
#pragma unroll
    for (int m = 0; m < 4; ++m)
#pragma unroll
      for (int n = 0; n < 2; ++n)
#pragma unroll
        for (int ks = 0; ks < 2; ++ks)
          acc[m][n] = __builtin_amdgcn_mfma_f32_16x16x32_bf16(a[m][ks], b[n][ks], acc[m][n], 0, 0, 0);
    __builtin_amdgcn_s_setprio(0);
    if (t + 2 < NT)
      asm volatile("s_waitcnt vmcnt(6)" ::: "memory");
    else if (t + 1 < NT)
      asm volatile("s_waitcnt vmcnt(0)" ::: "memory");
    __builtin_amdgcn_s_barrier();
  }

#pragma unroll
  for (int m = 0; m < 4; ++m) {
    int rbase = bm + wr * 64 + m * 16 + g * 4;
#pragma unroll
    for (int n = 0; n < 2; ++n) {
      int c = bn + wc * 32 + n * 16 + l15;
      float bv = bias[c];
#pragma unroll
      for (int j = 0; j < 4; ++j)
        o32[(size_t)(rbase + j) * N + c] = acc[m][n][j] + bv;
    }
  }
}

// ---------------- causal flash attention: KVBLK=128 (halved per-key chain overhead) ----------------
// Q (pre-scaled, log2 units), K: [H][S][64].  Vt: [H][64][S].  O: [S][1024] bf16.
// QBLK=128 (8 waves x 16 q-rows), KVBLK=128, double-buffered LDS (64KB),
// ONE barrier per tile; 17 avg tiles/block instead of 33 -> barrier/vmcnt/
// defer-max fixed costs halved per key. gload_lds-direct with pre-swizzled
// source (K: 128Brows, slot^= row&7 in 16B granules; V: 256B rows, same
// involution). Reads XOR with (l15&7)<<4 as before. 512 blocks, pair-balanced.
__global__ __launch_bounds__(512) void attn_kernel(const ushort* __restrict__ Q,
                                                   const ushort* __restrict__ Kg,
                                                   const ushort* __restrict__ Vtg,
                                                   ushort* __restrict__ O) {
  __shared__ ushort Ks[2][128 * 64];   // [key][d], swizzled
  __shared__ ushort Vs[2][64 * 128];   // [d][key], swizzled
  int bid = blockIdx.x;
  int h = bid & 15;
  int qt = (bid < 256) ? (31 - (bid >> 4)) : ((bid - 256) >> 4);
  int q0 = qt * 128;
  int tid = threadIdx.x, w = tid >> 6, lane = tid & 63;
  int l15 = lane & 15, g = lane >> 4;
  const ushort* qh = Q + (size_t)h * (S_LEN * DHEAD);
  const ushort* kh = Kg + (size_t)h * (S_LEN * DHEAD);
  const ushort* vh = Vtg + (size_t)h * (DHEAD * (size_t)S_LEN);

  // K staging: per wave 16 rows (2 instrs x 8 rows). lane -> row w*16+h*8+(l>>3),
  // source col swizzled ((l&7)^(l>>3))*8. Dest linear.
  int krow_l = lane >> 3;                       // 0..7 within 8-row group
  int kcol = ((lane & 7) ^ krow_l) * 8;         // swizzled source col (ushort)
  // V staging: per wave 8 d-rows (2 instrs x 4 rows). lane -> d = w*8+h*4+(l>>4),
  // slot l&15, source key-col = ((l&15) ^ (d&7))*8.
  int vrow_l = lane >> 4;                       // 0..3 within 4-row group
  int vslot = lane & 15;

  // read-side offsets
  int kxor = (l15 & 7) << 4;
  int koff0 = ((g * 16) ^ kxor) >> 1;
  int koff1 = ((64 + g * 16) ^ kxor) >> 1;
  int voff[8];
#pragma unroll
  for (int ct = 0; ct < 8; ++ct) voff[ct] = ((ct * 32 + g * 8) ^ kxor) >> 1;

  int qrow = q0 + w * 16 + l15;
  short8 aq[2];
#pragma unroll
  for (int t = 0; t < 2; ++t)
    aq[t] = *(const short8*)&qh[(size_t)qrow * DHEAD + t * 32 + g * 8];

  f32x4 acc_o[4];
#pragma unroll
  for (int dt = 0; dt < 4; ++dt) acc_o[dt] = (f32x4){0.f, 0.f, 0.f, 0.f};
  float m = -1e30f, l = 0.f;
  int last = qt;   // KV tiles of 128 keys: 0..qt

  auto stageKV = [&](int kv, int buf) {
#pragma unroll
    for (int hh2 = 0; hh2 < 2; ++hh2) {
      int krow = w * 16 + hh2 * 8 + krow_l;
      gload16(&kh[(size_t)(kv + krow) * DHEAD + kcol], &Ks[buf][w * 1024 + hh2 * 512]);
    }
#pragma unroll
    for (int hh2 = 0; hh2 < 2; ++hh2) {
      int d = w * 8 + hh2 * 4 + vrow_l;
      int vcol = (vslot ^ (d & 7)) * 8;
      gload16(&vh[(size_t)d * S_LEN + kv + vcol], &Vs[buf][w * 1024 + hh2 * 512]);
    }
  };

  // prologue: stage tile 0
  stageKV(0, 0);
  asm volatile("s_waitcnt vmcnt(0)" ::: "memory");
  __syncthreads();
  int cur = 0;

  for (int it = 0; it <= last; ++it) {
    int kv0 = it * 128;
    bool more = (it < last);
    const ushort* Kc = Ks[cur];
    const ushort* Vc = Vs[cur];

    // issue next tile's loads (latency hides under this tile's compute)
    if (more) stageKV(kv0 + 128, cur ^ 1);

    // swapped QK^T: accs[ct][j] = S^T[key = kv0+ct*16+g*4+j][q = l15-row]
    f32x4 accs[8];
#pragma unroll
    for (int ct = 0; ct < 8; ++ct) accs[ct] = (f32x4){0.f, 0.f, 0.f, 0.f};
    __builtin_amdgcn_s_setprio(1);
#pragma unroll
    for (int ct = 0; ct < 8; ++ct) {
      int rb = (ct * 16 + l15) * 64;
      short8 kf0 = *(const short8*)&Kc[rb + koff0];
      short8 kf1 = *(const short8*)&Kc[rb + koff1];
      accs[ct] = __builtin_amdgcn_mfma_f32_16x16x32_bf16(kf0, aq[0], accs[ct], 0, 0, 0);
      accs[ct] = __builtin_amdgcn_mfma_f32_16x16x32_bf16(kf1, aq[1], accs[ct], 0, 0, 0);
    }
    __builtin_amdgcn_s_setprio(0);

    if (it == qt) {  // diagonal tile: causal mask
#pragma unroll
      for (int ct = 0; ct < 8; ++ct) {
        int kbase = kv0 + ct * 16 + g * 4;
#pragma unroll
        for (int j = 0; j < 4; ++j)
          if (kbase + j > qrow) accs[ct][j] = -1e30f;
      }
    }

    // lane-local max tree over 32 values
    float t0 = fmaxf(fmaxf(accs[0][0], accs[0][1]), fmaxf(accs[0][2], accs[0][3]));
    float t1 = fmaxf(fmaxf(accs[1][0], accs[1][1]), fmaxf(accs[1][2], accs[1][3]));
    float t2m = fmaxf(fmaxf(accs[2][0], accs[2][1]), fmaxf(accs[2][2], accs[2][3]));
    float t3 = fmaxf(fmaxf(accs[3][0], accs[3][1]), fmaxf(accs[3][2], accs[3][3]));
    float t4 = fmaxf(fmaxf(accs[4][0], accs[4][1]), fmaxf(accs[4][2], accs[4][3]));
    float t5 = fmaxf(fmaxf(accs[5][0], accs[5][1]), fmaxf(accs[5][2], accs[5][3]));
    float t6 = fmaxf(fmaxf(accs[6][0], accs[6][1]), fmaxf(accs[6][2], accs[6][3]));
    float t7 = fmaxf(fmaxf(accs[7][0], accs[7][1]), fmaxf(accs[7][2], accs[7][3]));
    float pm = fmaxf(fmaxf(fmaxf(t0, t1), fmaxf(t2m, t3)),
                     fmaxf(fmaxf(t4, t5), fmaxf(t6, t7)));

    // defer-max: common path has NO cross-lane ops
    if (!__all(pm <= m + DEFER_THR)) {
      pm = fmaxf(pm, __shfl_xor(pm, 16));
      pm = fmaxf(pm, __shfl_xor(pm, 32));
      float mnew = fmaxf(m, pm);
      float corr = __builtin_amdgcn_exp2f(m - mnew);
      l *= corr; m = mnew;
#pragma unroll
      for (int dt = 0; dt < 4; ++dt)
#pragma unroll
        for (int j = 0; j < 4; ++j) acc_o[dt][j] *= corr;
    }

    // P = exp2(S - m), packed into K=32 permuted-slot fragments (4 groups)
    float rs = 0.f;
    short8 pk8[4];
#pragma unroll
    for (int t2 = 0; t2 < 4; ++t2) {
      float p0 = __builtin_amdgcn_exp2f(accs[2 * t2][0] - m);
      float p1 = __builtin_amdgcn_exp2f(accs[2 * t2][1] - m);
      float p2 = __builtin_amdgcn_exp2f(accs[2 * t2][2] - m);
      float p3 = __builtin_amdgcn_exp2f(accs[2 * t2][3] - m);
      float p4 = __builtin_amdgcn_exp2f(accs[2 * t2 + 1][0] - m);
      float p5 = __builtin_amdgcn_exp2f(accs[2 * t2 + 1][1] - m);
      float p6 = __builtin_amdgcn_exp2f(accs[2 * t2 + 1][2] - m);
      float p7 = __builtin_amdgcn_exp2f(accs[2 * t2 + 1][3] - m);
      rs += ((p0 + p1) + (p2 + p3)) + ((p4 + p5) + (p6 + p7));
      union { unsigned u[4]; short8 v; } pu;
      pu.u[0] = cvtpk_bf16(p0, p1);
      pu.u[1] = cvtpk_bf16(p2, p3);
      pu.u[2] = cvtpk_bf16(p4, p5);
      pu.u[3] = cvtpk_bf16(p6, p7);
      pk8[t2] = pu.v;
    }
    l += rs;   // per-lane partial

    // swapped PV, K=32 permuted slots: acc_o[dt][j] = O^T[d=dt*16+g*4+j][q=l15]
    __builtin_amdgcn_s_setprio(1);
#pragma unroll
    for (int dt = 0; dt < 4; ++dt) {
      int rb = (dt * 16 + l15) * 128;
#pragma unroll
      for (int t2 = 0; t2 < 4; ++t2) {
        union { short4v hh[2]; short8 v; } vu;
        vu.hh[0] = *(const short4v*)&Vc[rb + voff[2 * t2]];
        vu.hh[1] = *(const short4v*)&Vc[rb + voff[2 * t2 + 1]];
        acc_o[dt] = __builtin_amdgcn_mfma_f32_16x16x32_bf16(vu.v, pk8[t2], acc_o[dt], 0, 0, 0);
      }
    }
    __builtin_amdgcn_s_setprio(0);

    // drain own loads (landed during compute) + handoff
    asm volatile("s_waitcnt vmcnt(0)" ::: "memory");
    __syncthreads();
    cur ^= 1;
  }

  // epilogue: reduce l across the 4 g-groups, normalize, store
  l += __shfl_xor(l, 16);
  l += __shfl_xor(l, 32);
  float rl = (l > 0.f) ? 1.f / l : 0.f;
#pragma unroll
  for (int dt = 0; dt < 4; ++dt) {
    ushort4 o;
    o.x = f2bf(acc_o[dt][0] * rl);
    o.y = f2bf(acc_o[dt][1] * rl);
    o.z = f2bf(acc_o[dt][2] * rl);
    o.w = f2bf(acc_o[dt][3] * rl);
    *(ushort4*)&O[(size_t)qrow * D_EMB + h * DHEAD + dt * 16 + g * 4] = o;
  }
}

extern "C" void kernel_launch(void* const* d_in, const int* in_sizes, int n_in,
                              void* d_out, int out_size, void* d_ws, size_t ws_size,
                              hipStream_t stream) {
  const float* x = (const float*)d_in[0];
  const float* W_in = (const float*)d_in[1];
  const float* b_in = (const float*)d_in[2];
  const float* W_out = (const float*)d_in[3];
  const float* b_out = (const float*)d_in[4];
  float* out = (float*)d_out;
  ushort* ws = (ushort*)d_ws;

  prep_kernel<<<6144, 256, 0, stream>>>(x, W_in, W_out,
                                        ws + OFF_XB, ws + OFF_WINT, ws + OFF_WOUTT);
  gemm1_8phase<<<dim3(16, 16), 512, 0, stream>>>(
      ws + OFF_XB, ws + OFF_WINT, b_in, ws + OFF_Q);
  attn_kernel<<<512, 512, 0, stream>>>(
      ws + OFF_Q, ws + OFF_Q + 4194304u, ws + OFF_Q + 8388608u, ws + OFF_ATTN);
  gemm2_kernel<<<dim3(16, 32), 256, 0, stream>>>(
      ws + OFF_ATTN, ws + OFF_WOUTT, b_out, out, D_EMB, D_EMB);
}

// Round 21
// 120.129 us; speedup vs baseline: 1.2107x; 1.2107x over previous
//
#include <hip/hip_runtime.h>
#include <stdint.h>

#define S_LEN 4096
#define D_EMB 1024
#define NH 16
#define DHEAD 64
#define N3 3072

typedef __attribute__((ext_vector_type(8))) short short8;
typedef __attribute__((ext_vector_type(4))) short short4v;
typedef __attribute__((ext_vector_type(4))) float f32x4;

// workspace layout (ushort elements)
#define OFF_XB    0u         // x bf16 [4096][1024]
#define OFF_WINT  4194304u   // W_in^T bf16
#define OFF_WOUTT 7340032u   // W_out^T bf16 (live until gemm2)
#define OFF_Q     8388608u   // q [H][S][64], k [H][S][64], v^T [H][64][S]
#define OFF_ATTN  20971520u  // attn out [4096][1024] bf16

// 0.125 (1/sqrt(64)) * log2(e)
#define QSCALE 0.1803368801111204f
#define DEFER_THR 11.0f

__device__ __forceinline__ unsigned short f2bf(float f) {
  unsigned u = __float_as_uint(f);
  unsigned r = u + 0x7FFFu + ((u >> 16) & 1u);
  return (unsigned short)(r >> 16);
}
__device__ __forceinline__ unsigned cvtpk_bf16(float lo, float hi) {
  unsigned r;
  asm("v_cvt_pk_bf16_f32 %0, %1, %2" : "=v"(r) : "v"(lo), "v"(hi));
  return r;
}
__device__ __forceinline__ void gload16(const void* g, void* l) {
  __builtin_amdgcn_global_load_lds((const __attribute__((address_space(1))) void*)g,
                                   (__attribute__((address_space(3))) void*)l, 16, 0, 0);
}

// ---------------- fused prep: cvt x + transpose W_in + transpose W_out ----------------
__global__ __launch_bounds__(256) void prep_kernel(const float* __restrict__ x,
                                                   const float* __restrict__ W_in,
                                                   const float* __restrict__ W_out,
                                                   ushort* __restrict__ xb,
                                                   ushort* __restrict__ wint,
                                                   ushort* __restrict__ woutt) {
  __shared__ float tile[32][65];
  int b = blockIdx.x;
  int tid = threadIdx.x;
  if (b < 4096) {
    int i = (b * 256 + tid) * 4;
    float4 v = *(const float4*)(x + i);
    ushort4 o;
    o.x = f2bf(v.x); o.y = f2bf(v.y); o.z = f2bf(v.z); o.w = f2bf(v.w);
    *(ushort4*)(xb + i) = o;
    return;
  }
  const float* src;
  ushort* dst;
  int C, bx, by;
  if (b < 5632) {
    int t = b - 4096;
    src = W_in; dst = wint; C = N3;
    bx = t % 48; by = t / 48;
  } else {
    int t = b - 5632;
    src = W_out; dst = woutt; C = D_EMB;
    bx = t & 15; by = t >> 4;
  }
  const int R = D_EMB;
  int r0 = by * 32, c0 = bx * 64;
  int lr = tid >> 3, lc8 = (tid & 7) * 8;
  float4 v0 = *(const float4*)&src[(size_t)(r0 + lr) * C + c0 + lc8];
  float4 v1 = *(const float4*)&src[(size_t)(r0 + lr) * C + c0 + lc8 + 4];
  tile[lr][lc8 + 0] = v0.x; tile[lr][lc8 + 1] = v0.y;
  tile[lr][lc8 + 2] = v0.z; tile[lr][lc8 + 3] = v0.w;
  tile[lr][lc8 + 4] = v1.x; tile[lr][lc8 + 5] = v1.y;
  tile[lr][lc8 + 6] = v1.z; tile[lr][lc8 + 7] = v1.w;
  __syncthreads();
  int oc = tid >> 2, q = tid & 3;
  short8 o;
#pragma unroll
  for (int i = 0; i < 8; ++i) o[i] = (short)f2bf(tile[q * 8 + i][oc]);
  *(short8*)&dst[(size_t)(c0 + oc) * R + r0 + q * 8] = o;
}

// ---------------- GEMM1: 256x192 tile, 256 blocks, 8-phase counted-vmcnt (r18) ----------------
__global__ __launch_bounds__(512, 2) void gemm1_8phase(const ushort* __restrict__ A,
                                                       const ushort* __restrict__ Bt,
                                                       const float* __restrict__ bias,
                                                       ushort* __restrict__ o16) {
  __shared__ ushort L[57344];   // A: [0,32768), B: [32768,57344)
  const int K = 1024;
  int tid = threadIdx.x, w = tid >> 6, lane = tid & 63;
  int wr = w >> 2, wc = w & 3;
  int l15 = lane & 15, g = lane >> 4;
  int lr = lane >> 3, lc = lane & 7;
  int swcol = (lc ^ lr) * 8;
  int rxor = (l15 & 7) << 3;
  int id = blockIdx.y * 16 + blockIdx.x;
  int id2 = (id & 7) * 32 + (id >> 3);
  int bm = (id2 >> 4) * 256, bn = (id2 & 15) * 192;

  f32x4 acc[8][3];
#pragma unroll
  for (int m = 0; m < 8; ++m)
#pragma unroll
    for (int n = 0; n < 3; ++n) acc[m][n] = (f32x4){0.f, 0.f, 0.f, 0.f};

  auto stageA = [&](int t, int h) {
#pragma unroll
    for (int r2 = 0; r2 < 2; ++r2)
      gload16(A + (size_t)(bm + h * 128 + r2 * 64 + w * 8 + lr) * K + t * 64 + swcol,
              &L[(t & 1) * 16384 + h * 8192 + r2 * 4096 + w * 512]);
  };
  auto stageB0 = [&](int t) {
#pragma unroll
    for (int r2 = 0; r2 < 2; ++r2)
      gload16(Bt + (size_t)(bn + r2 * 64 + w * 8 + lr) * K + t * 64 + swcol,
              &L[32768 + (t & 1) * 12288 + r2 * 4096 + w * 512]);
  };
  auto stageB1 = [&](int t) {
    gload16(Bt + (size_t)(bn + 128 + w * 8 + lr) * K + t * 64 + swcol,
            &L[32768 + (t & 1) * 12288 + 8192 + w * 512]);
  };

  short8 bf[3][2], af[2][2];
  auto readB = [&](int tb) {
    int base = 32768 + tb * 12288;
#pragma unroll
    for (int n = 0; n < 3; ++n)
#pragma unroll
      for (int ks = 0; ks < 2; ++ks)
        bf[n][ks] = *(const short8*)&L[base + (wc * 48 + n * 16 + l15) * 64 + ((ks * 32 + g * 8) ^ rxor)];
  };
  auto readA2 = [&](int tb, int m0) {
    int base = tb * 16384 + wr * 8192;
#pragma unroll
    for (int mi = 0; mi < 2; ++mi)
#pragma unroll
      for (int ks = 0; ks < 2; ++ks)
        af[mi][ks] = *(const short8*)&L[base + ((m0 + mi) * 16 + l15) * 64 + ((ks * 32 + g * 8) ^ rxor)];
  };
  auto mfma6 = [&](int m0) {
#pragma unroll
    for (int mi = 0; mi < 2; ++mi)
#pragma unroll
      for (int n = 0; n < 3; ++n)
#pragma unroll
        for (int ks = 0; ks < 2; ++ks)
          acc[m0 + mi][n] =
              __builtin_amdgcn_mfma_f32_16x16x32_bf16(af[mi][ks], bf[n][ks], acc[m0 + mi][n], 0, 0, 0);
  };

#define BAR() __builtin_amdgcn_s_barrier()
#define LGK0() asm volatile("s_waitcnt lgkmcnt(0)" ::: "memory")
#define VM3() asm volatile("s_waitcnt vmcnt(3)" ::: "memory")
#define VM0() asm volatile("s_waitcnt vmcnt(0)" ::: "memory")

  stageA(0, 0); stageA(0, 1); stageB0(0); stageB1(0);
  stageB0(1); stageB1(1);
  VM3();
  BAR();

  for (int i = 0; i < 8; ++i) {
    int T = 2 * i;
    bool more = (T + 2 < 16);
    readB(0); readA2(0, 0); stageA(T + 1, 0);
    BAR(); LGK0();
    __builtin_amdgcn_s_setprio(1); mfma6(0); __builtin_amdgcn_s_setprio(0);
    BAR();
    readA2(0, 2); stageA(T + 1, 1);
    BAR(); LGK0();
    __builtin_amdgcn_s_setprio(1); mfma6(2); __builtin_amdgcn_s_setprio(0);
    BAR();
    readA2(0, 4); if (more) stageB0(T + 2);
    BAR(); LGK0();
    __builtin_amdgcn_s_setprio(1); mfma6(4); __builtin_amdgcn_s_setprio(0);
    BAR();
    readA2(0, 6); if (more) stageB1(T + 2);
    BAR(); LGK0();
    __builtin_amdgcn_s_setprio(1); mfma6(6); __builtin_amdgcn_s_setprio(0);
    if (more) VM3(); else VM0();
    BAR();
    readB(1); readA2(1, 0); if (more) stageA(T + 2, 0);
    BAR(); LGK0();
    __builtin_amdgcn_s_setprio(1); mfma6(0); __builtin_amdgcn_s_setprio(0);
    BAR();
    readA2(1, 2); if (more) stageA(T + 2, 1);
    BAR(); LGK0();
    __builtin_amdgcn_s_setprio(1); mfma6(2); __builtin_amdgcn_s_setprio(0);
    BAR();
    readA2(1, 4); if (more) stageB0(T + 3);
    BAR(); LGK0();
    __builtin_amdgcn_s_setprio(1); mfma6(4); __builtin_amdgcn_s_setprio(0);
    BAR();
    readA2(1, 6); if (more) stageB1(T + 3);
    BAR(); LGK0();
    __builtin_amdgcn_s_setprio(1); mfma6(6); __builtin_amdgcn_s_setprio(0);
    if (more) VM3(); else VM0();
    BAR();
  }
#undef BAR
#undef LGK0
#undef VM3
#undef VM0

#pragma unroll
  for (int m = 0; m < 8; ++m) {
    int rbase = bm + wr * 128 + m * 16 + g * 4;
#pragma unroll
    for (int n = 0; n < 3; ++n) {
      int c = bn + wc * 48 + n * 16 + l15;
      float bv = bias[c];
      int which = c >> 10, cc = c & 1023, hh = cc >> 6, dcol = cc & 63;
      if (which == 2) {
        ushort4 o;
        o.x = f2bf(acc[m][n][0] + bv);
        o.y = f2bf(acc[m][n][1] + bv);
        o.z = f2bf(acc[m][n][2] + bv);
        o.w = f2bf(acc[m][n][3] + bv);
        *(ushort4*)&o16[8388608u + (size_t)hh * (DHEAD * (size_t)S_LEN) +
                        (size_t)dcol * S_LEN + rbase] = o;
      } else {
        float qs = (which == 0) ? QSCALE : 1.0f;
        ushort* dst = o16 + (size_t)which * 4194304u +
                      (size_t)hh * (S_LEN * DHEAD) + dcol;
#pragma unroll
        for (int j = 0; j < 4; ++j)
          dst[(size_t)(rbase + j) * DHEAD] = f2bf((acc[m][n][j] + bv) * qs);
      }
    }
  }
}

// ---------------- GEMM2: 128x64 tile, 3-buffer counted-vmcnt pipeline (r17) ----------------
#define BK 64

__global__ __launch_bounds__(256) void gemm2_kernel(const ushort* __restrict__ A,
                                                    const ushort* __restrict__ Bt,
                                                    const float* __restrict__ bias,
                                                    float* __restrict__ o32,
                                                    int N, int K) {
  __shared__ ushort L[36864];   // 72KB
  int tid = threadIdx.x, w = tid >> 6, lane = tid & 63;
  int wr = w >> 1, wc = w & 1;
  int l15 = lane & 15, g = lane >> 4;
  int lr = lane >> 3, lc = lane & 7;
  int swcol = (lc ^ lr) * 8;
  int rxor = (l15 & 7) << 3;
  int gx = gridDim.x;
  int id = blockIdx.y * gx + blockIdx.x;
  int q8 = (gx * gridDim.y) >> 3;
  int id2 = (id & 7) * q8 + (id >> 3);
  int bm = (id2 / gx) * 128, bn = (id2 % gx) * 64;
  f32x4 acc[4][2];
#pragma unroll
  for (int m = 0; m < 4; ++m)
#pragma unroll
    for (int n = 0; n < 2; ++n) acc[m][n] = (f32x4){0.f, 0.f, 0.f, 0.f};

  auto stage = [&](int t) {
    int buf = t % 3;
#pragma unroll
    for (int i = 0; i < 4; ++i) {
      int ch = w * 4 + i;
      gload16(A + (size_t)(bm + ch * 8 + lr) * K + t * 64 + swcol,
              &L[buf * 8192 + ch * 512]);
    }
#pragma unroll
    for (int i = 0; i < 2; ++i) {
      int ch = w * 2 + i;
      gload16(Bt + (size_t)(bn + ch * 8 + lr) * K + t * 64 + swcol,
              &L[24576 + buf * 4096 + ch * 512]);
    }
  };

  const int NT = 16;
  stage(0); stage(1);
  asm volatile("s_waitcnt vmcnt(6)" ::: "memory");
  __builtin_amdgcn_s_barrier();

  for (int t = 0; t < NT; ++t) {
    int buf = t % 3;
    if (t + 2 < NT) stage(t + 2);
    const ushort* Ab = &L[buf * 8192];
    const ushort* Bb = &L[24576 + buf * 4096];
    short8 a[4][2], b[2][2];
#pragma unroll
    for (int m = 0; m < 4; ++m)
#pragma unroll
      for (int ks = 0; ks < 2; ++ks)
        a[m][ks] = *(const short8*)&Ab[(wr * 64 + m * 16 + l15) * 64 + ((ks * 32 + g * 8) ^ rxor)];
#pragma unroll
    for (int n = 0; n < 2; ++n)
#pragma unroll
      for (int ks = 0; ks < 2; ++ks)
        b[n][ks] = *(const short8*)&Bb[(wc * 32 + n * 16 + l15) * 64 + ((ks * 32 + g * 8) ^ rxor)];
    asm volatile("s_waitcnt lgkmcnt(0)" ::: "memory");
    __builtin_amdgcn_s_setprio(1);
#pragma unroll
    for (int m = 0; m < 4; ++m)
#pragma unroll
      for (int n = 0; n < 2; ++n)
#pragma unroll
        for (int ks = 0; ks < 2; ++ks)
          acc[m][n] = __builtin_amdgcn_mfma_f32_16x16x32_bf16(a[m][ks], b[n][ks], acc[m][n], 0, 0, 0);
    __builtin_amdgcn_s_setprio(0);
    if (t + 2 < NT)
      asm volatile("s_waitcnt vmcnt(6)" ::: "memory");
    else if (t + 1 < NT)
      asm volatile("s_waitcnt vmcnt(0)" ::: "memory");
    __builtin_amdgcn_s_barrier();
  }

#pragma unroll
  for (int m = 0; m < 4; ++m) {
    int rbase = bm + wr * 64 + m * 16 + g * 4;
#pragma unroll
    for (int n = 0; n < 2; ++n) {
      int c = bn + wc * 32 + n * 16 + l15;
      float bv = bias[c];
#pragma unroll
      for (int j = 0; j < 4; ++j)
        o32[(size_t)(rbase + j) * N + c] = acc[m][n][j] + bv;
    }
  }
}

// ---------------- causal flash attention (r16, frozen — structural optimum) ----------------
__global__ __launch_bounds__(512) void attn_kernel(const ushort* __restrict__ Q,
                                                   const ushort* __restrict__ Kg,
                                                   const ushort* __restrict__ Vtg,
                                                   ushort* __restrict__ O) {
  __shared__ ushort Ks[2][64 * 64];
  __shared__ ushort Vs[2][64 * 64];
  int bid = blockIdx.x;
  int h = bid & 15;
  int qt = (bid < 256) ? (31 - (bid >> 4)) : ((bid - 256) >> 4);
  int q0 = qt * 128;
  int tid = threadIdx.x, w = tid >> 6, lane = tid & 63;
  int l15 = lane & 15, g = lane >> 4;
  const ushort* qh = Q + (size_t)h * (S_LEN * DHEAD);
  const ushort* kh = Kg + (size_t)h * (S_LEN * DHEAD);
  const ushort* vh = Vtg + (size_t)h * (DHEAD * (size_t)S_LEN);
  int srow = w * 8 + (lane >> 3);
  int sgcol = (((lane & 7) ^ ((lane >> 3) & 7))) * 8;
  ushort* kdst0 = &Ks[0][w * 512];  ushort* kdst1 = &Ks[1][w * 512];
  ushort* vdst0 = &Vs[0][w * 512];  ushort* vdst1 = &Vs[1][w * 512];
  int kxor = (l15 & 7) << 4;
  int koff0 = ((g * 16) ^ kxor) >> 1;
  int koff1 = ((64 + g * 16) ^ kxor) >> 1;
  int voff[4];
#pragma unroll
  for (int ct = 0; ct < 4; ++ct) voff[ct] = ((ct * 32 + g * 8) ^ kxor) >> 1;

  int qrow = q0 + w * 16 + l15;
  short8 aq[2];
#pragma unroll
  for (int t = 0; t < 2; ++t)
    aq[t] = *(const short8*)&qh[(size_t)qrow * DHEAD + t * 32 + g * 8];

  f32x4 acc_o[4];
#pragma unroll
  for (int dt = 0; dt < 4; ++dt) acc_o[dt] = (f32x4){0.f, 0.f, 0.f, 0.f};
  float m = -1e30f, l = 0.f;
  int last = 2 * qt + 1;

  gload16(&kh[(size_t)srow * DHEAD + sgcol], kdst0);
  gload16(&vh[(size_t)srow * S_LEN + sgcol], vdst0);
  asm volatile("s_waitcnt vmcnt(0)" ::: "memory");
  __syncthreads();
  int cur = 0;

  for (int it = 0; it <= last; ++it) {
    int kv0 = it * 64;
    bool more = (it < last);
    const ushort* Kc = Ks[cur];
    const ushort* Vc = Vs[cur];

    if (more) {
      int kv1 = kv0 + 64;
      gload16(&kh[(size_t)(kv1 + srow) * DHEAD + sgcol], cur ? kdst0 : kdst1);
      gload16(&vh[(size_t)srow * S_LEN + kv1 + sgcol], cur ? vdst0 : vdst1);
    }

    f32x4 accs[4];
#pragma unroll
    for (int ct = 0; ct < 4; ++ct) accs[ct] = (f32x4){0.f, 0.f, 0.f, 0.f};
    __builtin_amdgcn_s_setprio(1);
#pragma unroll
    for (int ct = 0; ct < 4; ++ct) {
      int rb = (ct * 16 + l15) * 64;
      short8 kf0 = *(const short8*)&Kc[rb + koff0];
      short8 kf1 = *(const short8*)&Kc[rb + koff1];
      accs[ct] = __builtin_amdgcn_mfma_f32_16x16x32_bf16(kf0, aq[0], accs[ct], 0, 0, 0);
      accs[ct] = __builtin_amdgcn_mfma_f32_16x16x32_bf16(kf1, aq[1], accs[ct], 0, 0, 0);
    }
    __builtin_amdgcn_s_setprio(0);

    if (it >= 2 * qt) {
#pragma unroll
      for (int ct = 0; ct < 4; ++ct) {
        int kbase = kv0 + ct * 16 + g * 4;
#pragma unroll
        for (int j = 0; j < 4; ++j)
          if (kbase + j > qrow) accs[ct][j] = -1e30f;
      }
    }

    float a0 = fmaxf(fmaxf(accs[0][0], accs[0][1]), fmaxf(accs[0][2], accs[0][3]));
    float a1 = fmaxf(fmaxf(accs[1][0], accs[1][1]), fmaxf(accs[1][2], accs[1][3]));
    float a2 = fmaxf(fmaxf(accs[2][0], accs[2][1]), fmaxf(accs[2][2], accs[2][3]));
    float a3 = fmaxf(fmaxf(accs[3][0], accs[3][1]), fmaxf(accs[3][2], accs[3][3]));
    float pm = fmaxf(fmaxf(a0, a1), fmaxf(a2, a3));

    if (!__all(pm <= m + DEFER_THR)) {
      pm = fmaxf(pm, __shfl_xor(pm, 16));
      pm = fmaxf(pm, __shfl_xor(pm, 32));
      float mnew = fmaxf(m, pm);
      float corr = __builtin_amdgcn_exp2f(m - mnew);
      l *= corr; m = mnew;
#pragma unroll
      for (int dt = 0; dt < 4; ++dt)
#pragma unroll
        for (int j = 0; j < 4; ++j) acc_o[dt][j] *= corr;
    }

    float rs = 0.f;
    short8 pk8[2];
#pragma unroll
    for (int t2 = 0; t2 < 2; ++t2) {
      float p0 = __builtin_amdgcn_exp2f(accs[2 * t2][0] - m);
      float p1 = __builtin_amdgcn_exp2f(accs[2 * t2][1] - m);
      float p2 = __builtin_amdgcn_exp2f(accs[2 * t2][2] - m);
      float p3 = __builtin_amdgcn_exp2f(accs[2 * t2][3] - m);
      float p4 = __builtin_amdgcn_exp2f(accs[2 * t2 + 1][0] - m);
      float p5 = __builtin_amdgcn_exp2f(accs[2 * t2 + 1][1] - m);
      float p6 = __builtin_amdgcn_exp2f(accs[2 * t2 + 1][2] - m);
      float p7 = __builtin_amdgcn_exp2f(accs[2 * t2 + 1][3] - m);
      rs += ((p0 + p1) + (p2 + p3)) + ((p4 + p5) + (p6 + p7));
      union { unsigned u[4]; short8 v; } pu;
      pu.u[0] = cvtpk_bf16(p0, p1);
      pu.u[1] = cvtpk_bf16(p2, p3);
      pu.u[2] = cvtpk_bf16(p4, p5);
      pu.u[3] = cvtpk_bf16(p6, p7);
      pk8[t2] = pu.v;
    }
    l += rs;

    __builtin_amdgcn_s_setprio(1);
#pragma unroll
    for (int dt = 0; dt < 4; ++dt) {
      int rb = (dt * 16 + l15) * 64;
#pragma unroll
      for (int t2 = 0; t2 < 2; ++t2) {
        union { short4v hh[2]; short8 v; } vu;
        vu.hh[0] = *(const short4v*)&Vc[rb + voff[2 * t2]];
        vu.hh[1] = *(const short4v*)&Vc[rb + voff[2 * t2 + 1]];
        acc_o[dt] = __builtin_amdgcn_mfma_f32_16x16x32_bf16(vu.v, pk8[t2], acc_o[dt], 0, 0, 0);
      }
    }
    __builtin_amdgcn_s_setprio(0);

    asm volatile("s_waitcnt vmcnt(0)" ::: "memory");
    __syncthreads();
    cur ^= 1;
  }

  l += __shfl_xor(l, 16);
  l += __shfl_xor(l, 32);
  float rl = (l > 0.f) ? 1.f / l : 0.f;
#pragma unroll
  for (int dt = 0; dt < 4; ++dt) {
    ushort4 o;
    o.x = f2bf(acc_o[dt][0] * rl);
    o.y = f2bf(acc_o[dt][1] * rl);
    o.z = f2bf(acc_o[dt][2] * rl);
    o.w = f2bf(acc_o[dt][3] * rl);
    *(ushort4*)&O[(size_t)qrow * D_EMB + h * DHEAD + dt * 16 + g * 4] = o;
  }
}

extern "C" void kernel_launch(void* const* d_in, const int* in_sizes, int n_in,
                              void* d_out, int out_size, void* d_ws, size_t ws_size,
                              hipStream_t stream) {
  const float* x = (const float*)d_in[0];
  const float* W_in = (const float*)d_in[1];
  const float* b_in = (const float*)d_in[2];
  const float* W_out = (const float*)d_in[3];
  const float* b_out = (const float*)d_in[4];
  float* out = (float*)d_out;
  ushort* ws = (ushort*)d_ws;

  prep_kernel<<<6144, 256, 0, stream>>>(x, W_in, W_out,
                                        ws + OFF_XB, ws + OFF_WINT, ws + OFF_WOUTT);
  gemm1_8phase<<<dim3(16, 16), 512, 0, stream>>>(
      ws + OFF_XB, ws + OFF_WINT, b_in, ws + OFF_Q);
  attn_kernel<<<512, 512, 0, stream>>>(
      ws + OFF_Q, ws + OFF_Q + 4194304u, ws + OFF_Q + 8388608u, ws + OFF_ATTN);
  gemm2_kernel<<<dim3(16, 32), 256, 0, stream>>>(
      ws + OFF_ATTN, ws + OFF_WOUTT, b_out, out, D_EMB, D_EMB);
}